// Round 1
// baseline (2914.731 us; speedup 1.0000x reference)
//
#include <hip/hip_runtime.h>

// NodeMPNNLayer: fused MPNN layer, fp32 baseline.
//   Stage 1 (edge_mlp_scatter): per-edge MLP(cat[x[dst], ea, x[src]]) through
//     384->128 relu, 128->128 relu, 128->128, then atomic scatter-add into
//     sums[dst] + cnt[dst].
//   Stage 2 (node_fused): dh = sums/max(cnt,1); h = LN(x+dh); ff = relu(h@F1+bf1)@F2+bf2;
//     out = LN(h+ff).

#define NE 640000
#define NN 10000
#define DD 128
#define HIDN 256
#define EPSF 1e-6f

constexpr int BM  = 64;   // edges per block
constexpr int BK  = 32;   // K-chunk
constexpr int AST = 68;   // padded row stride for k-major LDS tiles (64 rows + pad)

__global__ __launch_bounds__(256, 2)
void edge_mlp_scatter(const float* __restrict__ x,
                      const int*   __restrict__ ei,
                      const float* __restrict__ ea,
                      const float* __restrict__ W1, const float* __restrict__ b1,
                      const float* __restrict__ W2, const float* __restrict__ b2,
                      const float* __restrict__ W3, const float* __restrict__ b3,
                      float* __restrict__ sums, float* __restrict__ cnt)
{
    __shared__ int   sSrc[BM];
    __shared__ int   sDst[BM];
    __shared__ float sAT[BK * AST];     // input chunk, k-major: [k][row]
    __shared__ float sB [BK * DD];      // weight chunk: [k][col]
    __shared__ float sActT[DD * AST];   // activations, k-major: [col-as-k][row]

    const int t  = threadIdx.x;
    const int r0 = (t >> 4) << 2;       // 4 rows per thread
    const int c0 = (t & 15) << 3;       // 8 cols per thread
    const long ebase = (long)blockIdx.x * BM;

    if (t < BM) {
        sSrc[t] = ei[ebase + t];            // edge_index[0] = src (j)
        sDst[t] = ei[(long)NE + ebase + t]; // edge_index[1] = dst (i)
    }
    __syncthreads();

    float acc[4][8];
#pragma unroll
    for (int i = 0; i < 4; ++i)
#pragma unroll
        for (int j = 0; j < 8; ++j) acc[i][j] = 0.f;

    // ---------------- layer 1: [64 x 384] @ [384 x 128] ----------------
    for (int kc = 0; kc < 384 / BK; ++kc) {
        const int kb = kc * BK;
        // stage gathered A^T (concat[x[dst], ea, x[src]]); branch is uniform per kc
#pragma unroll
        for (int p = 0; p < 2; ++p) {
            int fidx = t + p * 256;          // 0..511 -> 64 rows x 8 float4
            int row  = fidx >> 3;
            int c4   = (fidx & 7) << 2;
            int k    = kb + c4;
            float4 v;
            if (k < DD) {
                v = *(const float4*)(x + (long)sDst[row] * DD + k);
            } else if (k < 2 * DD) {
                v = *(const float4*)(ea + (ebase + row) * DD + (k - DD));
            } else {
                v = *(const float4*)(x + (long)sSrc[row] * DD + (k - 2 * DD));
            }
            sAT[(c4 + 0) * AST + row] = v.x;
            sAT[(c4 + 1) * AST + row] = v.y;
            sAT[(c4 + 2) * AST + row] = v.z;
            sAT[(c4 + 3) * AST + row] = v.w;
        }
        // stage W1 chunk
#pragma unroll
        for (int p = 0; p < 4; ++p) {
            int fidx = t + p * 256;          // 0..1023 -> 32 k x 32 float4
            int kr   = fidx >> 5;
            int col  = (fidx & 31) << 2;
            *(float4*)(sB + kr * DD + col) =
                *(const float4*)(W1 + (long)(kb + kr) * DD + col);
        }
        __syncthreads();
#pragma unroll 4
        for (int k = 0; k < BK; ++k) {
            float4 a   = *(const float4*)(sAT + k * AST + r0);
            float4 bl  = *(const float4*)(sB + k * DD + c0);
            float4 bh  = *(const float4*)(sB + k * DD + c0 + 4);
            float av[4] = {a.x, a.y, a.z, a.w};
            float bv[8] = {bl.x, bl.y, bl.z, bl.w, bh.x, bh.y, bh.z, bh.w};
#pragma unroll
            for (int i = 0; i < 4; ++i)
#pragma unroll
                for (int j = 0; j < 8; ++j)
                    acc[i][j] = fmaf(av[i], bv[j], acc[i][j]);
        }
        __syncthreads();
    }
    // bias + relu -> sActT (k-major)
#pragma unroll
    for (int j = 0; j < 8; ++j) {
        float bb = b1[c0 + j];
        float4 v = make_float4(fmaxf(acc[0][j] + bb, 0.f),
                               fmaxf(acc[1][j] + bb, 0.f),
                               fmaxf(acc[2][j] + bb, 0.f),
                               fmaxf(acc[3][j] + bb, 0.f));
        *(float4*)(sActT + (c0 + j) * AST + r0) = v;
    }
    __syncthreads();

    // ---------------- layers 2 & 3: [64 x 128] @ [128 x 128] ----------------
    for (int layer = 0; layer < 2; ++layer) {
        const float* W = (layer == 0) ? W2 : W3;
#pragma unroll
        for (int i = 0; i < 4; ++i)
#pragma unroll
            for (int j = 0; j < 8; ++j) acc[i][j] = 0.f;
        for (int kc = 0; kc < DD / BK; ++kc) {
            const int kb = kc * BK;
#pragma unroll
            for (int p = 0; p < 4; ++p) {
                int fidx = t + p * 256;
                int kr   = fidx >> 5;
                int col  = (fidx & 31) << 2;
                *(float4*)(sB + kr * DD + col) =
                    *(const float4*)(W + (long)(kb + kr) * DD + col);
            }
            __syncthreads();
#pragma unroll 4
            for (int k = 0; k < BK; ++k) {
                float4 a  = *(const float4*)(sActT + (kb + k) * AST + r0);
                float4 bl = *(const float4*)(sB + k * DD + c0);
                float4 bh = *(const float4*)(sB + k * DD + c0 + 4);
                float av[4] = {a.x, a.y, a.z, a.w};
                float bv[8] = {bl.x, bl.y, bl.z, bl.w, bh.x, bh.y, bh.z, bh.w};
#pragma unroll
                for (int i = 0; i < 4; ++i)
#pragma unroll
                    for (int j = 0; j < 8; ++j)
                        acc[i][j] = fmaf(av[i], bv[j], acc[i][j]);
            }
            __syncthreads();
        }
        if (layer == 0) {
#pragma unroll
            for (int j = 0; j < 8; ++j) {
                float bb = b2[c0 + j];
                float4 v = make_float4(fmaxf(acc[0][j] + bb, 0.f),
                                       fmaxf(acc[1][j] + bb, 0.f),
                                       fmaxf(acc[2][j] + bb, 0.f),
                                       fmaxf(acc[3][j] + bb, 0.f));
                *(float4*)(sActT + (c0 + j) * AST + r0) = v;
            }
            __syncthreads();
        }
    }

    // ---------------- scatter-add messages + counts ----------------
#pragma unroll
    for (int j = 0; j < 8; ++j) {
        float bb = b3[c0 + j];
#pragma unroll
        for (int i = 0; i < 4; ++i) {
            atomicAdd(sums + (long)sDst[r0 + i] * DD + (c0 + j), acc[i][j] + bb);
        }
    }
    if (t < BM) atomicAdd(cnt + sDst[t], 1.0f);
}

__global__ __launch_bounds__(256)
void node_fused(const float* __restrict__ x,
                const float* __restrict__ sums,
                const float* __restrict__ cnt,
                const float* __restrict__ F1, const float* __restrict__ bf1,
                const float* __restrict__ F2, const float* __restrict__ bf2,
                const float* __restrict__ g0, const float* __restrict__ be0,
                const float* __restrict__ g1, const float* __restrict__ be1,
                float* __restrict__ out)
{
    constexpr int NPB = 4;                 // nodes per block (one per wave)
    __shared__ float sh  [NPB][DD];
    __shared__ float shid[NPB][HIDN];
    __shared__ float sz  [NPB][DD];

    const int t = threadIdx.x;
    const int w = t >> 6;                  // wave id = local node id
    const int l = t & 63;
    const int node = blockIdx.x * NPB + w;
    const long base = (long)node * DD;

    // ---- dh + residual + LN1 (wave w owns node w) ----
    float inv = 1.0f / fmaxf(cnt[node], 1.0f);
    float y0 = x[base + l]      + sums[base + l]      * inv;
    float y1 = x[base + l + 64] + sums[base + l + 64] * inv;
    float s  = y0 + y1;
    float ss = y0 * y0 + y1 * y1;
#pragma unroll
    for (int off = 32; off > 0; off >>= 1) {
        s  += __shfl_down(s, off);
        ss += __shfl_down(ss, off);
    }
    s  = __shfl(s, 0);
    ss = __shfl(ss, 0);
    float mean = s * (1.0f / DD);
    float var  = ss * (1.0f / DD) - mean * mean;
    float rstd = rsqrtf(var + EPSF);
    sh[w][l]      = (y0 - mean) * rstd * g0[l]      + be0[l];
    sh[w][l + 64] = (y1 - mean) * rstd * g0[l + 64] + be0[l + 64];
    __syncthreads();

    // ---- hidden = relu(h @ F1 + bf1): thread t = hidden unit t, all 4 nodes ----
    float hacc[NPB];
    float bb1 = bf1[t];
#pragma unroll
    for (int v = 0; v < NPB; ++v) hacc[v] = bb1;
    for (int k = 0; k < DD; ++k) {
        float wv = F1[(long)k * HIDN + t];   // coalesced across t
#pragma unroll
        for (int v = 0; v < NPB; ++v) hacc[v] = fmaf(sh[v][k], wv, hacc[v]);
    }
#pragma unroll
    for (int v = 0; v < NPB; ++v) shid[v][t] = fmaxf(hacc[v], 0.f);
    __syncthreads();

    // ---- ff = hidden @ F2 + bf2; z = h + ff ----
    const int col = t & (DD - 1);
    const int v0  = (t >> 7) << 1;         // threads 0..127 -> nodes {0,1}, 128..255 -> {2,3}
    float o0 = bf2[col], o1 = bf2[col];
    for (int k = 0; k < HIDN; ++k) {
        float wv = F2[(long)k * DD + col];  // coalesced across col
        o0 = fmaf(shid[v0][k],     wv, o0);
        o1 = fmaf(shid[v0 + 1][k], wv, o1);
    }
    sz[v0][col]     = sh[v0][col]     + o0;
    sz[v0 + 1][col] = sh[v0 + 1][col] + o1;
    __syncthreads();

    // ---- LN2 (wave w owns node w) ----
    float z0 = sz[w][l], z1 = sz[w][l + 64];
    s  = z0 + z1;
    ss = z0 * z0 + z1 * z1;
#pragma unroll
    for (int off = 32; off > 0; off >>= 1) {
        s  += __shfl_down(s, off);
        ss += __shfl_down(ss, off);
    }
    s  = __shfl(s, 0);
    ss = __shfl(ss, 0);
    mean = s * (1.0f / DD);
    var  = ss * (1.0f / DD) - mean * mean;
    rstd = rsqrtf(var + EPSF);
    out[base + l]      = (z0 - mean) * rstd * g1[l]      + be1[l];
    out[base + l + 64] = (z1 - mean) * rstd * g1[l + 64] + be1[l + 64];
}

extern "C" void kernel_launch(void* const* d_in, const int* in_sizes, int n_in,
                              void* d_out, int out_size, void* d_ws, size_t ws_size,
                              hipStream_t stream)
{
    const float* x   = (const float*)d_in[0];
    const int*   ei  = (const int*)  d_in[1];
    const float* ea  = (const float*)d_in[2];
    const float* W1  = (const float*)d_in[3];
    const float* b1  = (const float*)d_in[4];
    const float* W2  = (const float*)d_in[5];
    const float* b2  = (const float*)d_in[6];
    const float* W3  = (const float*)d_in[7];
    const float* b3  = (const float*)d_in[8];
    const float* F1  = (const float*)d_in[9];
    const float* bf1 = (const float*)d_in[10];
    const float* F2  = (const float*)d_in[11];
    const float* bf2 = (const float*)d_in[12];
    const float* g0  = (const float*)d_in[13];
    const float* be0 = (const float*)d_in[14];
    const float* g1  = (const float*)d_in[15];
    const float* be1 = (const float*)d_in[16];
    float* out = (float*)d_out;

    float* sums = (float*)d_ws;                 // [NN][DD]
    float* cnt  = sums + (size_t)NN * DD;       // [NN]

    hipMemsetAsync(d_ws, 0, ((size_t)NN * DD + NN) * sizeof(float), stream);
    edge_mlp_scatter<<<NE / BM, 256, 0, stream>>>(x, ei, ea, W1, b1, W2, b2, W3, b3,
                                                  sums, cnt);
    node_fused<<<NN / 4, 256, 0, stream>>>(x, sums, cnt, F1, bf1, F2, bf2,
                                           g0, be0, g1, be1, out);
}

// Round 2
// 792.055 us; speedup vs baseline: 3.6800x; 3.6800x over previous
//
#include <hip/hip_runtime.h>

// NodeMPNNLayer — bf16-MFMA rewrite.
//   prep_weights: W1b/W2/W3 -> bf16, transposed [n][k], XOR-swizzled, in ws.
//   pq_kernel:    P' = x@W1[0:128] + b1,  Q = x@W1[256:384]   (bf16 in ws)
//   edge_mfma:    per 128-edge block: acc = bf16(ea)@W1b^T (MFMA), epi adds
//                 P'[dst]+Q[src], relu; two more 128x128 bf16 GEMMs; atomic
//                 scatter-add into sums[dst] + cnt.
//   node_fused:   dh=sums/max(cnt,1); LN; FF; LN  (fp32, 8 nodes/block).

#define NE 640000
#define NN 10000
#define DD 128
#define HIDN 256
#define EPSF 1e-6f

typedef __attribute__((ext_vector_type(8))) short short8;
typedef __attribute__((ext_vector_type(4))) float f32x4;

__device__ __forceinline__ unsigned short f2bf(float f) {
    union { float f; unsigned int u; } v; v.f = f;
    unsigned int r = v.u + 0x7FFFu + ((v.u >> 16) & 1u);
    return (unsigned short)(r >> 16);
}
__device__ __forceinline__ float bf2f(unsigned short h) {
    union { unsigned int u; float f; } v; v.u = ((unsigned int)h) << 16;
    return v.f;
}

// ---------------------------------------------------------------------------
// Weight prep: WT[layer][n][swz(k)] = bf16(W[k][n]); swizzle g' = (k>>3)^(n&7)
// so LDS staging is a straight linear copy and B-frag reads are ~2-way max.
// ---------------------------------------------------------------------------
__global__ void prep_weights(const float* __restrict__ W1,
                             const float* __restrict__ W2,
                             const float* __restrict__ W3,
                             unsigned short* __restrict__ WT)
{
    int g = blockIdx.x * 256 + threadIdx.x;      // 3*16384 = 49152
    int layer = g >> 14, r = g & 16383;
    int n = r >> 7, k = r & 127;
    const float* W = (layer == 0) ? (W1 + 128 * DD) : (layer == 1 ? W2 : W3);
    WT[layer * 16384 + n * 128 + ((((k >> 3) ^ (n & 7)) << 3) | (k & 7))] =
        f2bf(W[k * DD + n]);
}

// ---------------------------------------------------------------------------
// P' = x @ W1[0:128] + b1 ; Q = x @ W1[256:384]   (outputs bf16)
// ---------------------------------------------------------------------------
__global__ __launch_bounds__(256, 2)
void pq_kernel(const float* __restrict__ x, const float* __restrict__ W1,
               const float* __restrict__ b1,
               unsigned short* __restrict__ Pb, unsigned short* __restrict__ Qb)
{
    __shared__ float sXT[128 * 68];   // x^T tile, [k][row], stride 68
    __shared__ float sB[32 * 128];
    const int t = threadIdx.x;
    const int nb = blockIdx.x * 64;
    const int r0 = (t >> 4) << 2, c0 = (t & 15) << 3;

#pragma unroll
    for (int p = 0; p < 8; ++p) {
        int f = t + p * 256;                   // 2048 float4 = 64 rows x 32
        int row = f >> 5, c4 = (f & 31) << 2;
        int node = nb + row; if (node >= NN) node = NN - 1;
        float4 v = *(const float4*)(x + (long)node * DD + c4);
        sXT[(c4 + 0) * 68 + row] = v.x;
        sXT[(c4 + 1) * 68 + row] = v.y;
        sXT[(c4 + 2) * 68 + row] = v.z;
        sXT[(c4 + 3) * 68 + row] = v.w;
    }

    for (int pass = 0; pass < 2; ++pass) {
        const float* W = W1 + (pass == 0 ? 0 : 256 * DD);
        float acc[4][8];
#pragma unroll
        for (int i = 0; i < 4; ++i)
#pragma unroll
            for (int j = 0; j < 8; ++j) acc[i][j] = 0.f;

        for (int kc = 0; kc < 4; ++kc) {
            __syncthreads();
#pragma unroll
            for (int p = 0; p < 4; ++p) {
                int f = t + p * 256;           // 1024 float4 = 32 k x 32
                int kr = f >> 5, col = (f & 31) << 2;
                *(float4*)(sB + kr * 128 + col) =
                    *(const float4*)(W + (long)(kc * 32 + kr) * DD + col);
            }
            __syncthreads();
#pragma unroll 4
            for (int k = 0; k < 32; ++k) {
                float4 a  = *(const float4*)(sXT + (kc * 32 + k) * 68 + r0);
                float4 bl = *(const float4*)(sB + k * 128 + c0);
                float4 bh = *(const float4*)(sB + k * 128 + c0 + 4);
                float av[4] = {a.x, a.y, a.z, a.w};
                float bv[8] = {bl.x, bl.y, bl.z, bl.w, bh.x, bh.y, bh.z, bh.w};
#pragma unroll
                for (int i = 0; i < 4; ++i)
#pragma unroll
                    for (int j = 0; j < 8; ++j)
                        acc[i][j] = fmaf(av[i], bv[j], acc[i][j]);
            }
        }
        unsigned short* Out = (pass == 0) ? Pb : Qb;
#pragma unroll
        for (int i = 0; i < 4; ++i) {
            int node = nb + r0 + i;
            if (node < NN) {
                unsigned short tmp[8];
#pragma unroll
                for (int j = 0; j < 8; ++j) {
                    float v = acc[i][j] + (pass == 0 ? b1[c0 + j] : 0.f);
                    tmp[j] = f2bf(v);
                }
                *(uint4*)(Out + (long)node * 128 + c0) = *(uint4*)tmp;
            }
        }
    }
}

// ---------------------------------------------------------------------------
// Edge kernel: 128 edges/block, 4 waves; wave w owns rows 32w..32w+31.
// MFMA 16x16x32 bf16; A-tile + W-tile in XOR-swizzled LDS (64 KB total).
// ---------------------------------------------------------------------------
__device__ __forceinline__ const short8* frag(const unsigned short* buf,
                                              int row, int kc, int q)
{
    int g = (kc * 4 + q) ^ (row & 7);
    return (const short8*)(buf + row * 128 + g * 8);
}

__global__ __launch_bounds__(256, 2)
void edge_mfma(const float* __restrict__ ea, const int* __restrict__ ei,
               const unsigned short* __restrict__ WT,
               const unsigned short* __restrict__ Pb,
               const unsigned short* __restrict__ Qb,
               const float* __restrict__ b2, const float* __restrict__ b3,
               float* __restrict__ sums, float* __restrict__ cnt)
{
    __shared__ unsigned short sA[128 * 128];   // 32 KB
    __shared__ unsigned short sW[128 * 128];   // 32 KB

    const int t = threadIdx.x;
    const int wave = t >> 6, lane = t & 63;
    const int ln = lane & 15, q = lane >> 4;
    const int r0 = wave * 32;
    const long ebase = (long)blockIdx.x * 128;

    // per-lane edge indices for the 8 output rows this lane owns
    int drow[8], srow[8];
#pragma unroll
    for (int rt = 0; rt < 2; ++rt)
#pragma unroll
        for (int rg = 0; rg < 4; ++rg) {
            int row = r0 + rt * 16 + q * 4 + rg;
            drow[rt * 4 + rg] = ei[(long)NE + ebase + row];
            srow[rt * 4 + rg] = ei[ebase + row];
        }

    // stage A = bf16(ea tile), swizzled; coalesced float4 reads
#pragma unroll
    for (int p = 0; p < 16; ++p) {
        int f = t + p * 256;                   // 4096 float4 = 128 x 32
        int row = f >> 5, c4 = (f & 31) << 2;
        float4 v = *(const float4*)(ea + (ebase + row) * DD + c4);
        uint2 pk;
        pk.x = (unsigned)f2bf(v.x) | ((unsigned)f2bf(v.y) << 16);
        pk.y = (unsigned)f2bf(v.z) | ((unsigned)f2bf(v.w) << 16);
        int addr = row * 128 + ((((c4 >> 3) ^ (row & 7)) << 3) | (c4 & 7));
        *(uint2*)(sA + addr) = pk;
    }
    // stage W1b (pre-swizzled): pure linear copy
    {
        const uint4* src = (const uint4*)WT;
        uint4* dst = (uint4*)sW;
#pragma unroll
        for (int p = 0; p < 8; ++p) dst[t + p * 256] = src[t + p * 256];
    }
    __syncthreads();

    f32x4 acc[2][8];

    // ---- layer 1: bf16(ea) @ W1b^T ----
#pragma unroll
    for (int rt = 0; rt < 2; ++rt)
#pragma unroll
        for (int ct = 0; ct < 8; ++ct) acc[rt][ct] = (f32x4)(0.f);
#pragma unroll
    for (int kc = 0; kc < 4; ++kc) {
        short8 a0 = *frag(sA, r0 + ln,      kc, q);
        short8 a1 = *frag(sA, r0 + 16 + ln, kc, q);
#pragma unroll
        for (int ct = 0; ct < 8; ++ct) {
            short8 b = *frag(sW, ct * 16 + ln, kc, q);
            acc[0][ct] = __builtin_amdgcn_mfma_f32_16x16x32_bf16(a0, b, acc[0][ct], 0, 0, 0);
            acc[1][ct] = __builtin_amdgcn_mfma_f32_16x16x32_bf16(a1, b, acc[1][ct], 0, 0, 0);
        }
    }
    __syncthreads();
    // restage W2; epilogue-1: relu(acc + P'[dst] + Q[src]) -> sA (bf16)
    {
        const uint4* src = (const uint4*)(WT + 16384);
        uint4* dst = (uint4*)sW;
#pragma unroll
        for (int p = 0; p < 8; ++p) dst[t + p * 256] = src[t + p * 256];
    }
#pragma unroll
    for (int rt = 0; rt < 2; ++rt)
#pragma unroll
        for (int rg = 0; rg < 4; ++rg) {
            int row = r0 + rt * 16 + q * 4 + rg;
            long dof = (long)drow[rt * 4 + rg] * DD;
            long sof = (long)srow[rt * 4 + rg] * DD;
#pragma unroll
            for (int ct = 0; ct < 8; ++ct) {
                int col = ct * 16 + ln;
                float v = acc[rt][ct][rg] + bf2f(Pb[dof + col]) + bf2f(Qb[sof + col]);
                v = fmaxf(v, 0.f);
                sA[row * 128 + ((((col >> 3) ^ (row & 7)) << 3) | (col & 7))] = f2bf(v);
            }
        }
    __syncthreads();

    // ---- layer 2 ----
#pragma unroll
    for (int rt = 0; rt < 2; ++rt)
#pragma unroll
        for (int ct = 0; ct < 8; ++ct) acc[rt][ct] = (f32x4)(0.f);
#pragma unroll
    for (int kc = 0; kc < 4; ++kc) {
        short8 a0 = *frag(sA, r0 + ln,      kc, q);
        short8 a1 = *frag(sA, r0 + 16 + ln, kc, q);
#pragma unroll
        for (int ct = 0; ct < 8; ++ct) {
            short8 b = *frag(sW, ct * 16 + ln, kc, q);
            acc[0][ct] = __builtin_amdgcn_mfma_f32_16x16x32_bf16(a0, b, acc[0][ct], 0, 0, 0);
            acc[1][ct] = __builtin_amdgcn_mfma_f32_16x16x32_bf16(a1, b, acc[1][ct], 0, 0, 0);
        }
    }
    __syncthreads();
    // restage W3; epilogue-2: relu(acc + b2) -> sA
    {
        const uint4* src = (const uint4*)(WT + 2 * 16384);
        uint4* dst = (uint4*)sW;
#pragma unroll
        for (int p = 0; p < 8; ++p) dst[t + p * 256] = src[t + p * 256];
    }
    float bv2[8];
#pragma unroll
    for (int ct = 0; ct < 8; ++ct) bv2[ct] = b2[ct * 16 + ln];
#pragma unroll
    for (int rt = 0; rt < 2; ++rt)
#pragma unroll
        for (int rg = 0; rg < 4; ++rg) {
            int row = r0 + rt * 16 + q * 4 + rg;
#pragma unroll
            for (int ct = 0; ct < 8; ++ct) {
                int col = ct * 16 + ln;
                float v = fmaxf(acc[rt][ct][rg] + bv2[ct], 0.f);
                sA[row * 128 + ((((col >> 3) ^ (row & 7)) << 3) | (col & 7))] = f2bf(v);
            }
        }
    __syncthreads();

    // ---- layer 3 ----
#pragma unroll
    for (int rt = 0; rt < 2; ++rt)
#pragma unroll
        for (int ct = 0; ct < 8; ++ct) acc[rt][ct] = (f32x4)(0.f);
#pragma unroll
    for (int kc = 0; kc < 4; ++kc) {
        short8 a0 = *frag(sA, r0 + ln,      kc, q);
        short8 a1 = *frag(sA, r0 + 16 + ln, kc, q);
#pragma unroll
        for (int ct = 0; ct < 8; ++ct) {
            short8 b = *frag(sW, ct * 16 + ln, kc, q);
            acc[0][ct] = __builtin_amdgcn_mfma_f32_16x16x32_bf16(a0, b, acc[0][ct], 0, 0, 0);
            acc[1][ct] = __builtin_amdgcn_mfma_f32_16x16x32_bf16(a1, b, acc[1][ct], 0, 0, 0);
        }
    }
    // epilogue-3: scatter-add (acc + b3) into sums[dst]
    float bv3[8];
#pragma unroll
    for (int ct = 0; ct < 8; ++ct) bv3[ct] = b3[ct * 16 + ln];
#pragma unroll
    for (int rt = 0; rt < 2; ++rt)
#pragma unroll
        for (int rg = 0; rg < 4; ++rg) {
            long dof = (long)drow[rt * 4 + rg] * DD;
#pragma unroll
            for (int ct = 0; ct < 8; ++ct) {
                atomicAdd(sums + dof + ct * 16 + ln, acc[rt][ct][rg] + bv3[ct]);
            }
        }
    if (t < 128) atomicAdd(cnt + ei[(long)NE + ebase + t], 1.0f);
}

// ---------------------------------------------------------------------------
// Node stage: dh + LN1 + FF + LN2, fp32, 8 nodes/block.
// ---------------------------------------------------------------------------
__global__ __launch_bounds__(256)
void node_fused(const float* __restrict__ x,
                const float* __restrict__ sums, const float* __restrict__ cnt,
                const float* __restrict__ F1, const float* __restrict__ bf1,
                const float* __restrict__ F2, const float* __restrict__ bf2,
                const float* __restrict__ g0, const float* __restrict__ be0,
                const float* __restrict__ g1, const float* __restrict__ be1,
                float* __restrict__ out)
{
    constexpr int NPB = 8;
    __shared__ float sh[NPB][DD];
    __shared__ float shid[NPB][HIDN];
    __shared__ float sz[NPB][DD];

    const int t = threadIdx.x;
    const int wave = t >> 6, lane = t & 63;
    const int half = lane >> 5, l2 = lane & 31;
    const int nl = wave * 2 + half;
    const int node = blockIdx.x * NPB + nl;
    const long base = (long)node * DD;

    float inv = 1.0f / fmaxf(cnt[node], 1.0f);
    float y[4], s = 0.f, ss = 0.f;
#pragma unroll
    for (int e = 0; e < 4; ++e) {
        int c = l2 + 32 * e;
        y[e] = x[base + c] + sums[base + c] * inv;
        s += y[e]; ss += y[e] * y[e];
    }
#pragma unroll
    for (int off = 16; off > 0; off >>= 1) {
        s += __shfl_down(s, off, 32); ss += __shfl_down(ss, off, 32);
    }
    s = __shfl(s, 0, 32); ss = __shfl(ss, 0, 32);
    float mean = s * (1.0f / DD);
    float var  = ss * (1.0f / DD) - mean * mean;
    float rstd = rsqrtf(var + EPSF);
#pragma unroll
    for (int e = 0; e < 4; ++e) {
        int c = l2 + 32 * e;
        sh[nl][c] = (y[e] - mean) * rstd * g0[c] + be0[c];
    }
    __syncthreads();

    float hacc[NPB];
    float bb = bf1[t];
#pragma unroll
    for (int v = 0; v < NPB; ++v) hacc[v] = bb;
    for (int k = 0; k < DD; ++k) {
        float wv = F1[(long)k * HIDN + t];
#pragma unroll
        for (int v = 0; v < NPB; ++v) hacc[v] = fmaf(sh[v][k], wv, hacc[v]);
    }
#pragma unroll
    for (int v = 0; v < NPB; ++v) shid[v][t] = fmaxf(hacc[v], 0.f);
    __syncthreads();

    const int col = t & (DD - 1);
    const int grp = (t >> 7) * 4;
    float o[4];
#pragma unroll
    for (int v = 0; v < 4; ++v) o[v] = bf2[col];
    for (int k = 0; k < HIDN; ++k) {
        float wv = F2[(long)k * DD + col];
#pragma unroll
        for (int v = 0; v < 4; ++v) o[v] = fmaf(shid[grp + v][k], wv, o[v]);
    }
#pragma unroll
    for (int v = 0; v < 4; ++v) sz[grp + v][col] = sh[grp + v][col] + o[v];
    __syncthreads();

    float z[4]; s = 0.f; ss = 0.f;
#pragma unroll
    for (int e = 0; e < 4; ++e) {
        int c = l2 + 32 * e;
        z[e] = sz[nl][c]; s += z[e]; ss += z[e] * z[e];
    }
#pragma unroll
    for (int off = 16; off > 0; off >>= 1) {
        s += __shfl_down(s, off, 32); ss += __shfl_down(ss, off, 32);
    }
    s = __shfl(s, 0, 32); ss = __shfl(ss, 0, 32);
    mean = s * (1.0f / DD);
    var  = ss * (1.0f / DD) - mean * mean;
    rstd = rsqrtf(var + EPSF);
#pragma unroll
    for (int e = 0; e < 4; ++e) {
        int c = l2 + 32 * e;
        out[base + c] = (z[e] - mean) * rstd * g1[c] + be1[c];
    }
}

extern "C" void kernel_launch(void* const* d_in, const int* in_sizes, int n_in,
                              void* d_out, int out_size, void* d_ws, size_t ws_size,
                              hipStream_t stream)
{
    const float* x   = (const float*)d_in[0];
    const int*   ei  = (const int*)  d_in[1];
    const float* ea  = (const float*)d_in[2];
    const float* W1  = (const float*)d_in[3];
    const float* b1  = (const float*)d_in[4];
    const float* W2  = (const float*)d_in[5];
    const float* b2  = (const float*)d_in[6];
    const float* W3  = (const float*)d_in[7];
    const float* b3  = (const float*)d_in[8];
    const float* F1  = (const float*)d_in[9];
    const float* bf1 = (const float*)d_in[10];
    const float* F2  = (const float*)d_in[11];
    const float* bf2 = (const float*)d_in[12];
    const float* g0  = (const float*)d_in[13];
    const float* be0 = (const float*)d_in[14];
    const float* g1  = (const float*)d_in[15];
    const float* be1 = (const float*)d_in[16];
    float* out = (float*)d_out;

    char* ws = (char*)d_ws;
    float*          sums = (float*)(ws);                       // 5,120,000 B
    float*          cnt  = (float*)(ws + 5120000);             //    40,000 B
    unsigned short* WT   = (unsigned short*)(ws + 5160192);    //    98,304 B
    unsigned short* Pb   = (unsigned short*)(ws + 5258752);    // 2,560,000 B
    unsigned short* Qb   = (unsigned short*)(ws + 7818752);    // 2,560,000 B
    // total ~10.4 MB

    hipMemsetAsync(ws, 0, 5160000, stream);                    // sums + cnt
    prep_weights<<<192, 256, 0, stream>>>(W1, W2, W3, WT);
    pq_kernel<<<(NN + 63) / 64, 256, 0, stream>>>(x, W1, b1, Pb, Qb);
    edge_mfma<<<NE / 128, 256, 0, stream>>>(ea, ei, WT, Pb, Qb, b2, b3, sums, cnt);
    node_fused<<<NN / 8, 256, 0, stream>>>(x, sums, cnt, F1, bf1, F2, bf2,
                                           g0, be0, g1, be1, out);
}